// Round 5
// baseline (143424.670 us; speedup 1.0000x reference)
//
#include <hip/hip_runtime.h>
#include <math.h>

// NCA: B=8, H=W=256, C=16, 16 steps. fp32.
// R4 post-mortem: GEMM2's "#pragma unroll 4" left jj runtime -> acc0[jj]
// runtime-indexed -> ENTIRE acc array in scratch -> GEMM1 ran on scratch
// (2.3 GB/dispatch scratch writes). Rule: register arrays need FULL unroll,
// and small enough total footprint (<~80 floats) that nothing spills.
// R5: 512 thr/block. Phase2: thread=(pg pixel, jg of 8; 32 j each).
//   acc[32]+dx[16] ~75 regs peak. GEMM2 fully unrolled. shfl reduce-and-
//   distribute (masks 4,2,1, static indices) -> each lane stores its float2.

#define HW 256
#define NPIX (8*HW*HW)   // 524288

__device__ __forceinline__ float2 f2max(float2 a, float2 b) {
    return make_float2(fmaxf(a.x,b.x), fmaxf(a.y,b.y));
}

// Precompute sobel bank (6 filters, 7x7, normalized).
__global__ void init_kernel(const float* __restrict__ W0,
                            float* __restrict__ filt) {
    int t = blockIdx.x * blockDim.x + threadIdx.x;
    if (t < 6) {
        int f = t;
        int size = 3 + 2*(f >> 1);
        int p0 = (7 - size) >> 1;
        int isY = f & 1;
        float vals[49];
        float norm = 0.f;
        for (int a = 0; a < 7; a++) {
            for (int b = 0; b < 7; b++) {
                float v = 0.f;
                if (a >= p0 && a < p0+size && b >= p0 && b < p0+size) {
                    float fy = (float)(a - 3), fx = (float)(b - 3);
                    float den = fx*fx + fy*fy;
                    if (den == 0.f) den = 1.f;
                    v = (isY ? fy : fx) / den;
                }
                vals[a*7+b] = v;
                norm += fabsf(v);
            }
        }
        float inv = 1.f / norm;
        for (int i = 0; i < 49; i++) filt[f*49 + i] = vals[i] * inv;
    }
}

// One 8x8 pixel tile per block, 512 threads.
// Phase 1: thread=(pixel p=t&63, cpair q=t>>6 of 8): conv/pools -> perc LDS.
// Phase 2: thread=(pg=t>>3 pixel, jg=t&7): 32-j register tile.
__launch_bounds__(512, 4)
__global__ void step_main(const float* __restrict__ x,
                          float* __restrict__ xmid,
                          float* __restrict__ alpha_out,
                          float* __restrict__ prelife_out,
                          const float* __restrict__ filt_g,
                          const float* __restrict__ W0,
                          const float* __restrict__ b0,
                          const float* __restrict__ W1,
                          const float* __restrict__ stoch_s) {
    __shared__ float xs[14*14*20];     // halo tile, 16ch padded to 20
    __shared__ float filt_s[294];
    __shared__ float perc[64*132];     // 128-ch percept per pixel, +4 pad

    const int t   = threadIdx.x;
    const int b   = blockIdx.z;
    const int ty0 = blockIdx.y * 8;
    const int tx0 = blockIdx.x * 8;

    for (int i = t; i < 294; i += 512) filt_s[i] = filt_g[i];

    // stage x tile + halo (zero pad = conv's zero padding)
    for (int v = t; v < 784; v += 512) {          // 14*14*4 float4s
        int c4  = v & 3;
        int cell = v >> 2;
        int ly = cell / 14;
        int lx = cell - ly*14;
        int gy = ty0 + ly - 3, gx = tx0 + lx - 3;
        float4 val = make_float4(0.f,0.f,0.f,0.f);
        if ((unsigned)gy < 256u && (unsigned)gx < 256u)
            val = *(const float4*)&x[((((b<<8) + gy)<<8) + gx)*16 + (c4<<2)];
        *(float4*)&xs[cell*20 + (c4<<2)] = val;
    }
    __syncthreads();

    {   // ---- phase 1: conv + pools -> perc (2 channels per thread) ----
        const int p  = t & 63;
        const int q  = t >> 6;         // 0..7 channel pair (uniform per wave)
        const int c2 = q << 1;
        const int py = p >> 3, px = p & 7;
        const int gy = ty0 + py, gx = tx0 + px;

        float2 y2[6];
        #pragma unroll
        for (int f = 0; f < 6; f++) y2[f] = make_float2(0.f, 0.f);

        #pragma unroll
        for (int a = 0; a < 7; a++) {
            #pragma unroll
            for (int bb = 0; bb < 7; bb++) {
                float2 xv = *(const float2*)&xs[((py+a)*14 + (px+bb))*20 + c2];
                #pragma unroll
                for (int f = 0; f < 6; f++) {
                    float w = filt_s[f*49 + a*7 + bb];   // broadcast
                    y2[f].x = fmaf(w, xv.x, y2[f].x);
                    y2[f].y = fmaf(w, xv.y, y2[f].y);
                }
            }
        }
        float2 m5 = make_float2(-INFINITY, -INFINITY);
        #pragma unroll
        for (int dy = -2; dy <= 2; dy++) {
            #pragma unroll
            for (int dx2 = -2; dx2 <= 2; dx2++) {
                if ((unsigned)(gy+dy) < 256u && (unsigned)(gx+dx2) < 256u)
                    m5 = f2max(m5, *(const float2*)&xs[((py+3+dy)*14 + (px+3+dx2))*20 + c2]);
            }
        }
        // perc: [0:16)=x, [16+f*16+c)=y (f-major), [112:128)=pool5
        float2 xc = *(const float2*)&xs[((py+3)*14 + (px+3))*20 + c2];
        *(float2*)&perc[p*132 + c2] = xc;
        #pragma unroll
        for (int f = 0; f < 6; f++)
            *(float2*)&perc[p*132 + 16 + f*16 + c2] = y2[f];
        *(float2*)&perc[p*132 + 112 + c2] = m5;

        if (q == 0) {
            float pre = -INFINITY;
            #pragma unroll
            for (int dy = -1; dy <= 1; dy++) {
                #pragma unroll
                for (int dx2 = -1; dx2 <= 1; dx2++) {
                    if ((unsigned)(gy+dy) < 256u && (unsigned)(gx+dx2) < 256u)
                        pre = fmaxf(pre, xs[((py+3+dy)*14 + (px+3+dx2))*20 + 3]);
                }
            }
            prelife_out[(b << 16) + (gy << 8) + gx] = (pre > 0.1f) ? 1.f : 0.f;
        }
    }
    __syncthreads();

    // ---- phase 2: MLP, 32 j per thread ----
    const int pg = t >> 3;         // pixel 0..63
    const int jg = t & 7;          // j-range [jg*32, jg*32+32)
    const int jbase = jg << 5;
    const float* percP = &perc[pg * 132];

    float acc[32];
    #pragma unroll
    for (int i = 0; i < 32; i++) acc[i] = 0.f;

    #pragma unroll 1
    for (int k = 0; k < 128; k++) {
        float a0 = percP[k];                       // LDS, 8-lane broadcast
        const float4* wrow = (const float4*)(W0 + (k << 8) + jbase);
        #pragma unroll
        for (int qq = 0; qq < 8; qq++) {
            float4 wv = wrow[qq];
            acc[qq*4+0] = fmaf(a0, wv.x, acc[qq*4+0]);
            acc[qq*4+1] = fmaf(a0, wv.y, acc[qq*4+1]);
            acc[qq*4+2] = fmaf(a0, wv.z, acc[qq*4+2]);
            acc[qq*4+3] = fmaf(a0, wv.w, acc[qq*4+3]);
        }
    }

    // h = relu(acc + b0)
    {
        const float4* b0v = (const float4*)(b0 + jbase);
        #pragma unroll
        for (int qq = 0; qq < 8; qq++) {
            float4 bv = b0v[qq];
            acc[qq*4+0] = fmaxf(acc[qq*4+0] + bv.x, 0.f);
            acc[qq*4+1] = fmaxf(acc[qq*4+1] + bv.y, 0.f);
            acc[qq*4+2] = fmaxf(acc[qq*4+2] + bv.z, 0.f);
            acc[qq*4+3] = fmaxf(acc[qq*4+3] + bv.w, 0.f);
        }
    }

    // GEMM2: dx[16] += h[jj] * W1[row].  FULL unroll: acc[jj] must be static.
    float dx[16];
    #pragma unroll
    for (int c = 0; c < 16; c++) dx[c] = 0.f;
    #pragma unroll
    for (int jj = 0; jj < 32; jj++) {
        const float4* w1r = (const float4*)(W1 + ((jbase + jj) << 4));
        float4 wa = w1r[0], wb = w1r[1], wc = w1r[2], wd = w1r[3];
        float h = acc[jj];
        dx[0]  = fmaf(h, wa.x, dx[0]);  dx[1]  = fmaf(h, wa.y, dx[1]);
        dx[2]  = fmaf(h, wa.z, dx[2]);  dx[3]  = fmaf(h, wa.w, dx[3]);
        dx[4]  = fmaf(h, wb.x, dx[4]);  dx[5]  = fmaf(h, wb.y, dx[5]);
        dx[6]  = fmaf(h, wb.z, dx[6]);  dx[7]  = fmaf(h, wb.w, dx[7]);
        dx[8]  = fmaf(h, wc.x, dx[8]);  dx[9]  = fmaf(h, wc.y, dx[9]);
        dx[10] = fmaf(h, wc.z, dx[10]); dx[11] = fmaf(h, wc.w, dx[11]);
        dx[12] = fmaf(h, wd.x, dx[12]); dx[13] = fmaf(h, wd.y, dx[13]);
        dx[14] = fmaf(h, wd.z, dx[14]); dx[15] = fmaf(h, wd.w, dx[15]);
    }

    // reduce-and-distribute over the 8 jg lanes (static indices, value selects)
    float e[8];
    #pragma unroll
    for (int c = 0; c < 8; c++) {
        float lo = dx[c]     + __shfl_xor(dx[c],     4);
        float hi = dx[c + 8] + __shfl_xor(dx[c + 8], 4);
        e[c] = (jg & 4) ? hi : lo;
    }
    float f4r[4];
    #pragma unroll
    for (int c = 0; c < 4; c++) {
        float lo = e[c]     + __shfl_xor(e[c],     2);
        float hi = e[c + 4] + __shfl_xor(e[c + 4], 2);
        f4r[c] = (jg & 2) ? hi : lo;
    }
    float g0, g1;
    {
        float lo0 = f4r[0] + __shfl_xor(f4r[0], 1);
        float hi0 = f4r[2] + __shfl_xor(f4r[2], 1);
        g0 = (jg & 1) ? hi0 : lo0;
        float lo1 = f4r[1] + __shfl_xor(f4r[1], 1);
        float hi1 = f4r[3] + __shfl_xor(f4r[3], 1);
        g1 = (jg & 1) ? hi1 : lo1;
    }
    // lane jg now holds complete dx for channels {2jg, 2jg+1}

    const int ppy = pg >> 3, ppx = pg & 7;
    const int pix2 = (b << 16) + ((ty0 + ppy) << 8) + (tx0 + ppx);
    float fire = (stoch_s[pix2] > 0.5f) ? 1.f : 0.f;
    float2 xc2 = *(const float2*)&perc[pg*132 + (jg << 1)];
    float xn0 = fmaf(fire, g0, xc2.x);
    float xn1 = fmaf(fire, g1, xc2.y);
    *(float2*)&xmid[((size_t)pix2 << 4) + (jg << 1)] = make_float2(xn0, xn1);
    if (jg == 1) alpha_out[pix2] = xn1;   // channel 3
}

// In-place life masking: reads alpha_new from the separate plane (race-free).
__global__ void step_mask(float* __restrict__ xbuf,
                          const float* __restrict__ alpha,
                          const float* __restrict__ prelife,
                          const float* __restrict__ valid) {
    int pix = blockIdx.x * 256 + threadIdx.x;
    int b = pix >> 16;
    int y = (pix >> 8) & 255;
    int x = pix & 255;
    float m = -INFINITY;
    #pragma unroll
    for (int dy = -1; dy <= 1; dy++) {
        #pragma unroll
        for (int dxo = -1; dxo <= 1; dxo++) {
            int yy = y + dy, xx = x + dxo;
            if ((unsigned)yy < 256u && (unsigned)xx < 256u)
                m = fmaxf(m, alpha[(b << 16) + (yy << 8) + xx]);
        }
    }
    float life = (prelife[pix] != 0.f && m > 0.1f) ? 1.f : 0.f;
    float s = life * valid[pix];
    float4* xp = (float4*)&xbuf[(size_t)pix << 4];
    #pragma unroll
    for (int i = 0; i < 4; i++) {
        float4 v = xp[i];
        v.x *= s; v.y *= s; v.z *= s; v.w *= s;
        xp[i] = v;
    }
}

extern "C" void kernel_launch(void* const* d_in, const int* in_sizes, int n_in,
                              void* d_out, int out_size, void* d_ws, size_t ws_size,
                              hipStream_t stream) {
    const float* x0    = (const float*)d_in[0];
    const float* valid = (const float*)d_in[1];
    const float* stoch = (const float*)d_in[2];
    const float* W0    = (const float*)d_in[3];
    const float* b0    = (const float*)d_in[4];
    const float* W1    = (const float*)d_in[5];

    float* ws      = (float*)d_ws;
    float* xA      = ws;                 // 8388608 floats
    float* alpha   = ws + 8388608;       // 524288
    float* prelife = ws + 8912896;       // 524288
    float* filt    = ws + 9437184;       // 294 (+pad)
    float* out     = (float*)d_out;

    init_kernel<<<1, 64, 0, stream>>>(W0, filt);

    const float* src = x0;
    for (int k = 1; k <= 16; k++) {
        float* dst = (k & 1) ? xA : out;   // step 16 (even) lands in d_out
        step_main<<<dim3(32,32,8), 512, 0, stream>>>(
            src, dst, alpha, prelife, filt, W0, b0, W1,
            stoch + (size_t)(k-1)*NPIX);
        step_mask<<<NPIX/256, 256, 0, stream>>>(dst, alpha, prelife, valid);
        src = dst;
    }
}

// Round 6
// 132212.195 us; speedup vs baseline: 1.0848x; 1.0848x over previous
//
#include <hip/hip_runtime.h>
#include <math.h>

// NCA: B=8, H=W=256, C=16, 16 steps. fp32.
// R5 post-mortem: __launch_bounds__(512,4) acted as CUDA min-BLOCKS-per-CU ->
// 8 waves/SIMD -> 64-VGPR cap -> acc[32]+dx[16] forced to scratch (5.3 GB
// writes). Meta-rule after R2..R5: the allocator never grants >128 regs here;
// only safe design = peak live < 64 regs, literal indices everywhere.
// R6: phase2 thread=(pixel, jg of 4). 64 j's in 8 chunks of 8 NAMED scalar
// h-accs; GEMM2 folds each chunk into dx[16] immediately. Peak live ~45.

#define HW 256
#define NPIX (8*HW*HW)   // 524288

__device__ __forceinline__ float4 f4max(float4 a, float4 b) {
    return make_float4(fmaxf(a.x,b.x), fmaxf(a.y,b.y), fmaxf(a.z,b.z), fmaxf(a.w,b.w));
}

// Precompute sobel bank (6 filters, 7x7, normalized).
__global__ void init_kernel(const float* __restrict__ W0,
                            float* __restrict__ filt) {
    int t = blockIdx.x * blockDim.x + threadIdx.x;
    if (t < 6) {
        int f = t;
        int size = 3 + 2*(f >> 1);
        int p0 = (7 - size) >> 1;
        int isY = f & 1;
        float vals[49];
        float norm = 0.f;
        for (int a = 0; a < 7; a++) {
            for (int b = 0; b < 7; b++) {
                float v = 0.f;
                if (a >= p0 && a < p0+size && b >= p0 && b < p0+size) {
                    float fy = (float)(a - 3), fx = (float)(b - 3);
                    float den = fx*fx + fy*fy;
                    if (den == 0.f) den = 1.f;
                    v = (isY ? fy : fx) / den;
                }
                vals[a*7+b] = v;
                norm += fabsf(v);
            }
        }
        float inv = 1.f / norm;
        for (int i = 0; i < 49; i++) filt[f*49 + i] = vals[i] * inv;
    }
}

// One 8x8 pixel tile per block, 256 threads.
// Phase 1: thread=(pixel p=t&63, chan-quad q=t>>6): conv/pools -> perc LDS.
// Phase 2: thread=(pg=t>>2 pixel, jg=t&3): 64 j's in 8 chunks of 8.
__launch_bounds__(256)
__global__ void step_main(const float* __restrict__ x,
                          float* __restrict__ xmid,
                          float* __restrict__ alpha_out,
                          float* __restrict__ prelife_out,
                          const float* __restrict__ filt_g,
                          const float* __restrict__ W0,
                          const float* __restrict__ b0,
                          const float* __restrict__ W1,
                          const float* __restrict__ stoch_s) {
    __shared__ float xs[14*14*20];     // halo tile, 16ch padded to 20
    __shared__ float filt_s[294];
    __shared__ float perc[64*132];     // 128-ch percept per pixel, +4 pad

    const int t   = threadIdx.x;
    const int b   = blockIdx.z;
    const int ty0 = blockIdx.y * 8;
    const int tx0 = blockIdx.x * 8;

    for (int i = t; i < 294; i += 256) filt_s[i] = filt_g[i];

    // stage x tile + halo (zero pad = conv's zero padding)
    for (int v = t; v < 784; v += 256) {          // 14*14*4 float4s
        int c4  = v & 3;
        int cell = v >> 2;
        int ly = cell / 14;
        int lx = cell - ly*14;
        int gy = ty0 + ly - 3, gx = tx0 + lx - 3;
        float4 val = make_float4(0.f,0.f,0.f,0.f);
        if ((unsigned)gy < 256u && (unsigned)gx < 256u)
            val = *(const float4*)&x[((((b<<8) + gy)<<8) + gx)*16 + (c4<<2)];
        *(float4*)&xs[cell*20 + (c4<<2)] = val;
    }
    __syncthreads();

    {   // ---- phase 1: conv + pools -> perc ----
        const int p  = t & 63;
        const int q  = t >> 6;
        const int py = p >> 3, px = p & 7;
        const int gy = ty0 + py, gx = tx0 + px;
        const int q4 = q << 2;

        float4 y4[6];
        #pragma unroll
        for (int f = 0; f < 6; f++) y4[f] = make_float4(0.f,0.f,0.f,0.f);

        #pragma unroll
        for (int a = 0; a < 7; a++) {
            #pragma unroll
            for (int bb = 0; bb < 7; bb++) {
                float4 xv = *(const float4*)&xs[((py+a)*14 + (px+bb))*20 + q4];
                #pragma unroll
                for (int f = 0; f < 6; f++) {
                    float w = filt_s[f*49 + a*7 + bb];
                    y4[f].x = fmaf(w, xv.x, y4[f].x);
                    y4[f].y = fmaf(w, xv.y, y4[f].y);
                    y4[f].z = fmaf(w, xv.z, y4[f].z);
                    y4[f].w = fmaf(w, xv.w, y4[f].w);
                }
            }
        }
        float4 m5 = make_float4(-INFINITY,-INFINITY,-INFINITY,-INFINITY);
        #pragma unroll
        for (int dy = -2; dy <= 2; dy++) {
            #pragma unroll
            for (int dx2 = -2; dx2 <= 2; dx2++) {
                if ((unsigned)(gy+dy) < 256u && (unsigned)(gx+dx2) < 256u)
                    m5 = f4max(m5, *(const float4*)&xs[((py+3+dy)*14 + (px+3+dx2))*20 + q4]);
            }
        }
        // perc: [0:16)=x, [16+f*16+c)=y (f-major), [112:128)=pool5
        float4 xc = *(const float4*)&xs[((py+3)*14 + (px+3))*20 + q4];
        *(float4*)&perc[p*132 + q4] = xc;
        #pragma unroll
        for (int f = 0; f < 6; f++)
            *(float4*)&perc[p*132 + 16 + f*16 + q4] = y4[f];
        *(float4*)&perc[p*132 + 112 + q4] = m5;

        if (q == 0) {
            float pre = -INFINITY;
            #pragma unroll
            for (int dy = -1; dy <= 1; dy++) {
                #pragma unroll
                for (int dx2 = -1; dx2 <= 1; dx2++) {
                    if ((unsigned)(gy+dy) < 256u && (unsigned)(gx+dx2) < 256u)
                        pre = fmaxf(pre, xs[((py+3+dy)*14 + (px+3+dx2))*20 + 3]);
                }
            }
            prelife_out[(b << 16) + (gy << 8) + gx] = (pre > 0.1f) ? 1.f : 0.f;
        }
    }
    __syncthreads();

    // ---- phase 2: MLP ----
    const int pg = t >> 2;         // pixel 0..63
    const int jg = t & 3;          // 0..3; owns j in [jg*64, jg*64+64)
    const float* percP = &perc[pg * 132];

    float dx[16];
    #pragma unroll
    for (int c = 0; c < 16; c++) dx[c] = 0.f;

    // fold one h into dx[16] (all literal indices)
    #define G2(hv, jdx) { \
        const float4* w1r = (const float4*)(W1 + ((jdx) << 4)); \
        float4 wa = w1r[0], wb = w1r[1], wc = w1r[2], wd = w1r[3]; \
        dx[0]  = fmaf(hv, wa.x, dx[0]);  dx[1]  = fmaf(hv, wa.y, dx[1]); \
        dx[2]  = fmaf(hv, wa.z, dx[2]);  dx[3]  = fmaf(hv, wa.w, dx[3]); \
        dx[4]  = fmaf(hv, wb.x, dx[4]);  dx[5]  = fmaf(hv, wb.y, dx[5]); \
        dx[6]  = fmaf(hv, wb.z, dx[6]);  dx[7]  = fmaf(hv, wb.w, dx[7]); \
        dx[8]  = fmaf(hv, wc.x, dx[8]);  dx[9]  = fmaf(hv, wc.y, dx[9]); \
        dx[10] = fmaf(hv, wc.z, dx[10]); dx[11] = fmaf(hv, wc.w, dx[11]); \
        dx[12] = fmaf(hv, wd.x, dx[12]); dx[13] = fmaf(hv, wd.y, dx[13]); \
        dx[14] = fmaf(hv, wd.z, dx[14]); dx[15] = fmaf(hv, wd.w, dx[15]); }

    #pragma unroll 1
    for (int ch = 0; ch < 8; ch++) {
        const int jbase = (jg << 6) + (ch << 3);   // 8 j's this chunk
        float h0=0.f,h1=0.f,h2=0.f,h3=0.f,h4=0.f,h5=0.f,h6=0.f,h7=0.f;
        const float* W0c = W0 + jbase;
        #pragma unroll 1
        for (int k = 0; k < 128; k++) {
            float a = percP[k];                     // LDS broadcast
            const float4* w = (const float4*)(W0c + (k << 8));
            float4 wA = w[0], wB = w[1];
            h0 = fmaf(a, wA.x, h0); h1 = fmaf(a, wA.y, h1);
            h2 = fmaf(a, wA.z, h2); h3 = fmaf(a, wA.w, h3);
            h4 = fmaf(a, wB.x, h4); h5 = fmaf(a, wB.y, h5);
            h6 = fmaf(a, wB.z, h6); h7 = fmaf(a, wB.w, h7);
        }
        const float4* b0v = (const float4*)(b0 + jbase);
        float4 bA = b0v[0], bB = b0v[1];
        h0 = fmaxf(h0 + bA.x, 0.f); h1 = fmaxf(h1 + bA.y, 0.f);
        h2 = fmaxf(h2 + bA.z, 0.f); h3 = fmaxf(h3 + bA.w, 0.f);
        h4 = fmaxf(h4 + bB.x, 0.f); h5 = fmaxf(h5 + bB.y, 0.f);
        h6 = fmaxf(h6 + bB.z, 0.f); h7 = fmaxf(h7 + bB.w, 0.f);
        G2(h0, jbase + 0); G2(h1, jbase + 1);
        G2(h2, jbase + 2); G2(h3, jbase + 3);
        G2(h4, jbase + 4); G2(h5, jbase + 5);
        G2(h6, jbase + 6); G2(h7, jbase + 7);
    }
    #undef G2

    // reduce-and-distribute over 4 jg lanes (masks 1,2; value selects only)
    float e[8];
    #pragma unroll
    for (int c = 0; c < 8; c++) {
        float lo = dx[c]     + __shfl_xor(dx[c],     1);
        float hi = dx[c + 8] + __shfl_xor(dx[c + 8], 1);
        e[c] = (jg & 1) ? hi : lo;
    }
    float fr[4];
    #pragma unroll
    for (int c = 0; c < 4; c++) {
        float lo = e[c]     + __shfl_xor(e[c],     2);
        float hi = e[c + 4] + __shfl_xor(e[c + 4], 2);
        fr[c] = (jg & 2) ? hi : lo;
    }
    // lane jg owns channel-quad base:
    const int cbase = ((jg & 1) << 3) | ((jg & 2) << 1);   // 0,8,4,12

    const int ppy = pg >> 3, ppx = pg & 7;
    const int pix2 = (b << 16) + ((ty0 + ppy) << 8) + (tx0 + ppx);
    float fire = (stoch_s[pix2] > 0.5f) ? 1.f : 0.f;
    float4 xc2 = *(const float4*)&perc[pg*132 + cbase];
    float4 xn;
    xn.x = fmaf(fire, fr[0], xc2.x);
    xn.y = fmaf(fire, fr[1], xc2.y);
    xn.z = fmaf(fire, fr[2], xc2.z);
    xn.w = fmaf(fire, fr[3], xc2.w);
    *(float4*)&xmid[((size_t)pix2 << 4) + cbase] = xn;
    if (jg == 0) alpha_out[pix2] = xn.w;   // cbase=0 -> .w is channel 3
}

// In-place life masking: reads alpha_new from the separate plane (race-free).
__global__ void step_mask(float* __restrict__ xbuf,
                          const float* __restrict__ alpha,
                          const float* __restrict__ prelife,
                          const float* __restrict__ valid) {
    int pix = blockIdx.x * 256 + threadIdx.x;
    int b = pix >> 16;
    int y = (pix >> 8) & 255;
    int x = pix & 255;
    float m = -INFINITY;
    #pragma unroll
    for (int dy = -1; dy <= 1; dy++) {
        #pragma unroll
        for (int dxo = -1; dxo <= 1; dxo++) {
            int yy = y + dy, xx = x + dxo;
            if ((unsigned)yy < 256u && (unsigned)xx < 256u)
                m = fmaxf(m, alpha[(b << 16) + (yy << 8) + xx]);
        }
    }
    float life = (prelife[pix] != 0.f && m > 0.1f) ? 1.f : 0.f;
    float s = life * valid[pix];
    float4* xp = (float4*)&xbuf[(size_t)pix << 4];
    #pragma unroll
    for (int i = 0; i < 4; i++) {
        float4 v = xp[i];
        v.x *= s; v.y *= s; v.z *= s; v.w *= s;
        xp[i] = v;
    }
}

extern "C" void kernel_launch(void* const* d_in, const int* in_sizes, int n_in,
                              void* d_out, int out_size, void* d_ws, size_t ws_size,
                              hipStream_t stream) {
    const float* x0    = (const float*)d_in[0];
    const float* valid = (const float*)d_in[1];
    const float* stoch = (const float*)d_in[2];
    const float* W0    = (const float*)d_in[3];
    const float* b0    = (const float*)d_in[4];
    const float* W1    = (const float*)d_in[5];

    float* ws      = (float*)d_ws;
    float* xA      = ws;                 // 8388608 floats
    float* alpha   = ws + 8388608;       // 524288
    float* prelife = ws + 8912896;       // 524288
    float* filt    = ws + 9437184;       // 294 (+pad)
    float* out     = (float*)d_out;

    init_kernel<<<1, 64, 0, stream>>>(W0, filt);

    const float* src = x0;
    for (int k = 1; k <= 16; k++) {
        float* dst = (k & 1) ? xA : out;   // step 16 (even) lands in d_out
        step_main<<<dim3(32,32,8), 256, 0, stream>>>(
            src, dst, alpha, prelife, filt, W0, b0, W1,
            stoch + (size_t)(k-1)*NPIX);
        step_mask<<<NPIX/256, 256, 0, stream>>>(dst, alpha, prelife, valid);
        src = dst;
    }
}

// Round 7
// 32703.983 us; speedup vs baseline: 4.3855x; 4.0427x over previous
//
#include <hip/hip_runtime.h>
#include <math.h>

// NCA: B=8, H=W=256, C=16, 16 steps. fp32.
// R6 post-mortem: spill GONE (WRITE 41MB) but VGPR=256 (greedy scheduler,
// no occupancy target) + per-iter dependent global W0 loads (128KB/block
// working set >> L1) -> latency-bound at 1-2 waves/SIMD, VALUBusy 5%.
// R7: W0 staged to LDS in 8 j-chunks of 32 (16KB, aliased over dead conv
// tile; LDS stays 51.4KB -> 3 blocks/CU). k-loop reads weights from LDS
// (broadcast, conflict-free). __launch_bounds__(256,3) pins VGPR<=~168.
// Register footprint: 8 named h + dx[16] ~= 45 live.

#define HW 256
#define NPIX (8*HW*HW)   // 524288

__device__ __forceinline__ float4 f4max(float4 a, float4 b) {
    return make_float4(fmaxf(a.x,b.x), fmaxf(a.y,b.y), fmaxf(a.z,b.z), fmaxf(a.w,b.w));
}

// Precompute sobel bank (6 filters, 7x7, normalized).
__global__ void init_kernel(const float* __restrict__ W0,
                            float* __restrict__ filt) {
    int t = blockIdx.x * blockDim.x + threadIdx.x;
    if (t < 6) {
        int f = t;
        int size = 3 + 2*(f >> 1);
        int p0 = (7 - size) >> 1;
        int isY = f & 1;
        float vals[49];
        float norm = 0.f;
        for (int a = 0; a < 7; a++) {
            for (int b = 0; b < 7; b++) {
                float v = 0.f;
                if (a >= p0 && a < p0+size && b >= p0 && b < p0+size) {
                    float fy = (float)(a - 3), fx = (float)(b - 3);
                    float den = fx*fx + fy*fy;
                    if (den == 0.f) den = 1.f;
                    v = (isY ? fy : fx) / den;
                }
                vals[a*7+b] = v;
                norm += fabsf(v);
            }
        }
        float inv = 1.f / norm;
        for (int i = 0; i < 49; i++) filt[f*49 + i] = vals[i] * inv;
    }
}

// One 8x8 pixel tile per block, 256 threads.
// Phase 1: thread=(pixel p=t&63, chan-quad q=t>>6): conv/pools -> perc LDS.
// Phase 2: 8 j-chunks of 32: stage W0 chunk to LDS, thread=(pg=t>>2, jg=t&3)
//          computes 8 named h's over k=128 from LDS, folds into dx[16].
__launch_bounds__(256, 3)
__global__ void step_main(const float* __restrict__ x,
                          float* __restrict__ xmid,
                          float* __restrict__ alpha_out,
                          float* __restrict__ prelife_out,
                          const float* __restrict__ filt_g,
                          const float* __restrict__ W0,
                          const float* __restrict__ b0,
                          const float* __restrict__ W1,
                          const float* __restrict__ stoch_s) {
    // smem carve: [0:4096) xs (phase1, 3920 used) ALIAS w0s (phase2, 4096)
    //             [4096:4396) filt   [4396:12844) perc 64x132
    __shared__ float smem[12844];
    float* xs     = smem;          // 14*14*20 = 3920
    float* w0s    = smem;          // 128 k x 32 j = 4096 (phase 2)
    float* filt_s = smem + 4096;   // 294
    float* perc   = smem + 4396;   // 64*132 = 8448

    const int t   = threadIdx.x;
    const int b   = blockIdx.z;
    const int ty0 = blockIdx.y * 8;
    const int tx0 = blockIdx.x * 8;

    for (int i = t; i < 294; i += 256) filt_s[i] = filt_g[i];

    // stage x tile + halo (zero pad = conv's zero padding)
    for (int v = t; v < 784; v += 256) {          // 14*14*4 float4s
        int c4  = v & 3;
        int cell = v >> 2;
        int ly = cell / 14;
        int lx = cell - ly*14;
        int gy = ty0 + ly - 3, gx = tx0 + lx - 3;
        float4 val = make_float4(0.f,0.f,0.f,0.f);
        if ((unsigned)gy < 256u && (unsigned)gx < 256u)
            val = *(const float4*)&x[((((b<<8) + gy)<<8) + gx)*16 + (c4<<2)];
        *(float4*)&xs[cell*20 + (c4<<2)] = val;
    }
    __syncthreads();

    {   // ---- phase 1: conv + pools -> perc ----
        const int p  = t & 63;
        const int q  = t >> 6;
        const int py = p >> 3, px = p & 7;
        const int gy = ty0 + py, gx = tx0 + px;
        const int q4 = q << 2;

        float4 y4[6];
        #pragma unroll
        for (int f = 0; f < 6; f++) y4[f] = make_float4(0.f,0.f,0.f,0.f);

        #pragma unroll
        for (int a = 0; a < 7; a++) {
            #pragma unroll
            for (int bb = 0; bb < 7; bb++) {
                float4 xv = *(const float4*)&xs[((py+a)*14 + (px+bb))*20 + q4];
                #pragma unroll
                for (int f = 0; f < 6; f++) {
                    float w = filt_s[f*49 + a*7 + bb];
                    y4[f].x = fmaf(w, xv.x, y4[f].x);
                    y4[f].y = fmaf(w, xv.y, y4[f].y);
                    y4[f].z = fmaf(w, xv.z, y4[f].z);
                    y4[f].w = fmaf(w, xv.w, y4[f].w);
                }
            }
        }
        float4 m5 = make_float4(-INFINITY,-INFINITY,-INFINITY,-INFINITY);
        #pragma unroll
        for (int dy = -2; dy <= 2; dy++) {
            #pragma unroll
            for (int dx2 = -2; dx2 <= 2; dx2++) {
                if ((unsigned)(gy+dy) < 256u && (unsigned)(gx+dx2) < 256u)
                    m5 = f4max(m5, *(const float4*)&xs[((py+3+dy)*14 + (px+3+dx2))*20 + q4]);
            }
        }
        // perc: [0:16)=x, [16+f*16+c)=y (f-major), [112:128)=pool5
        float4 xc = *(const float4*)&xs[((py+3)*14 + (px+3))*20 + q4];
        *(float4*)&perc[p*132 + q4] = xc;
        #pragma unroll
        for (int f = 0; f < 6; f++)
            *(float4*)&perc[p*132 + 16 + f*16 + q4] = y4[f];
        *(float4*)&perc[p*132 + 112 + q4] = m5;

        if (q == 0) {
            float pre = -INFINITY;
            #pragma unroll
            for (int dy = -1; dy <= 1; dy++) {
                #pragma unroll
                for (int dx2 = -1; dx2 <= 1; dx2++) {
                    if ((unsigned)(gy+dy) < 256u && (unsigned)(gx+dx2) < 256u)
                        pre = fmaxf(pre, xs[((py+3+dy)*14 + (px+3+dx2))*20 + 3]);
                }
            }
            prelife_out[(b << 16) + (gy << 8) + gx] = (pre > 0.1f) ? 1.f : 0.f;
        }
    }
    // NOTE: xs is dead from here; its space becomes w0s.

    // ---- phase 2: MLP ----
    const int pg = t >> 2;         // pixel 0..63
    const int jg = t & 3;          // owns 8 j within each 32-j chunk
    const float* percP = &perc[pg * 132];

    float dx[16];
    #pragma unroll
    for (int c = 0; c < 16; c++) dx[c] = 0.f;

    #define G2(hv, jdx) { \
        const float4* w1r = (const float4*)(W1 + ((jdx) << 4)); \
        float4 wa = w1r[0], wb = w1r[1], wc = w1r[2], wd = w1r[3]; \
        dx[0]  = fmaf(hv, wa.x, dx[0]);  dx[1]  = fmaf(hv, wa.y, dx[1]); \
        dx[2]  = fmaf(hv, wa.z, dx[2]);  dx[3]  = fmaf(hv, wa.w, dx[3]); \
        dx[4]  = fmaf(hv, wb.x, dx[4]);  dx[5]  = fmaf(hv, wb.y, dx[5]); \
        dx[6]  = fmaf(hv, wb.z, dx[6]);  dx[7]  = fmaf(hv, wb.w, dx[7]); \
        dx[8]  = fmaf(hv, wc.x, dx[8]);  dx[9]  = fmaf(hv, wc.y, dx[9]); \
        dx[10] = fmaf(hv, wc.z, dx[10]); dx[11] = fmaf(hv, wc.w, dx[11]); \
        dx[12] = fmaf(hv, wd.x, dx[12]); dx[13] = fmaf(hv, wd.y, dx[13]); \
        dx[14] = fmaf(hv, wd.z, dx[14]); dx[15] = fmaf(hv, wd.w, dx[15]); }

    #pragma unroll 1
    for (int jc = 0; jc < 8; jc++) {
        __syncthreads();   // previous chunk's k-loop done before overwrite
        // stage W0[:, jc*32 .. +32) -> w0s[k][32], contiguous (idx*4 words)
        #pragma unroll
        for (int r = 0; r < 4; r++) {
            int idx = (r << 8) + t;     // 0..1023 float4s
            *(float4*)&w0s[idx << 2] =
                *(const float4*)&W0[((idx >> 3) << 8) + (jc << 5) + ((idx & 7) << 2)];
        }
        __syncthreads();

        const int jbase = (jc << 5) + (jg << 3);   // global j of h0
        float h0=0.f,h1=0.f,h2=0.f,h3=0.f,h4=0.f,h5=0.f,h6=0.f,h7=0.f;
        const int wof = jg << 3;
        #pragma unroll 4
        for (int k = 0; k < 128; k++) {
            float a = percP[k];                     // LDS, 4-lane broadcast
            float4 wA = *(const float4*)&w0s[(k << 5) + wof];
            float4 wB = *(const float4*)&w0s[(k << 5) + wof + 4];
            h0 = fmaf(a, wA.x, h0); h1 = fmaf(a, wA.y, h1);
            h2 = fmaf(a, wA.z, h2); h3 = fmaf(a, wA.w, h3);
            h4 = fmaf(a, wB.x, h4); h5 = fmaf(a, wB.y, h5);
            h6 = fmaf(a, wB.z, h6); h7 = fmaf(a, wB.w, h7);
        }
        const float4* b0v = (const float4*)(b0 + jbase);
        float4 bA = b0v[0], bB = b0v[1];
        h0 = fmaxf(h0 + bA.x, 0.f); h1 = fmaxf(h1 + bA.y, 0.f);
        h2 = fmaxf(h2 + bA.z, 0.f); h3 = fmaxf(h3 + bA.w, 0.f);
        h4 = fmaxf(h4 + bB.x, 0.f); h5 = fmaxf(h5 + bB.y, 0.f);
        h6 = fmaxf(h6 + bB.z, 0.f); h7 = fmaxf(h7 + bB.w, 0.f);
        G2(h0, jbase + 0); G2(h1, jbase + 1);
        G2(h2, jbase + 2); G2(h3, jbase + 3);
        G2(h4, jbase + 4); G2(h5, jbase + 5);
        G2(h6, jbase + 6); G2(h7, jbase + 7);
    }
    #undef G2

    // reduce-and-distribute over 4 jg lanes (masks 1,2; value selects only)
    float e[8];
    #pragma unroll
    for (int c = 0; c < 8; c++) {
        float lo = dx[c]     + __shfl_xor(dx[c],     1);
        float hi = dx[c + 8] + __shfl_xor(dx[c + 8], 1);
        e[c] = (jg & 1) ? hi : lo;
    }
    float fr[4];
    #pragma unroll
    for (int c = 0; c < 4; c++) {
        float lo = e[c]     + __shfl_xor(e[c],     2);
        float hi = e[c + 4] + __shfl_xor(e[c + 4], 2);
        fr[c] = (jg & 2) ? hi : lo;
    }
    // lane jg owns channel-quad base:
    const int cbase = ((jg & 1) << 3) | ((jg & 2) << 1);   // 0,8,4,12

    const int ppy = pg >> 3, ppx = pg & 7;
    const int pix2 = (b << 16) + ((ty0 + ppy) << 8) + (tx0 + ppx);
    float fire = (stoch_s[pix2] > 0.5f) ? 1.f : 0.f;
    float4 xc2 = *(const float4*)&perc[pg*132 + cbase];
    float4 xn;
    xn.x = fmaf(fire, fr[0], xc2.x);
    xn.y = fmaf(fire, fr[1], xc2.y);
    xn.z = fmaf(fire, fr[2], xc2.z);
    xn.w = fmaf(fire, fr[3], xc2.w);
    *(float4*)&xmid[((size_t)pix2 << 4) + cbase] = xn;
    if (jg == 0) alpha_out[pix2] = xn.w;   // cbase=0 -> .w is channel 3
}

// In-place life masking: reads alpha_new from the separate plane (race-free).
__global__ void step_mask(float* __restrict__ xbuf,
                          const float* __restrict__ alpha,
                          const float* __restrict__ prelife,
                          const float* __restrict__ valid) {
    int pix = blockIdx.x * 256 + threadIdx.x;
    int b = pix >> 16;
    int y = (pix >> 8) & 255;
    int x = pix & 255;
    float m = -INFINITY;
    #pragma unroll
    for (int dy = -1; dy <= 1; dy++) {
        #pragma unroll
        for (int dxo = -1; dxo <= 1; dxo++) {
            int yy = y + dy, xx = x + dxo;
            if ((unsigned)yy < 256u && (unsigned)xx < 256u)
                m = fmaxf(m, alpha[(b << 16) + (yy << 8) + xx]);
        }
    }
    float life = (prelife[pix] != 0.f && m > 0.1f) ? 1.f : 0.f;
    float s = life * valid[pix];
    float4* xp = (float4*)&xbuf[(size_t)pix << 4];
    #pragma unroll
    for (int i = 0; i < 4; i++) {
        float4 v = xp[i];
        v.x *= s; v.y *= s; v.z *= s; v.w *= s;
        xp[i] = v;
    }
}

extern "C" void kernel_launch(void* const* d_in, const int* in_sizes, int n_in,
                              void* d_out, int out_size, void* d_ws, size_t ws_size,
                              hipStream_t stream) {
    const float* x0    = (const float*)d_in[0];
    const float* valid = (const float*)d_in[1];
    const float* stoch = (const float*)d_in[2];
    const float* W0    = (const float*)d_in[3];
    const float* b0    = (const float*)d_in[4];
    const float* W1    = (const float*)d_in[5];

    float* ws      = (float*)d_ws;
    float* xA      = ws;                 // 8388608 floats
    float* alpha   = ws + 8388608;       // 524288
    float* prelife = ws + 8912896;       // 524288
    float* filt    = ws + 9437184;       // 294 (+pad)
    float* out     = (float*)d_out;

    init_kernel<<<1, 64, 0, stream>>>(W0, filt);

    const float* src = x0;
    for (int k = 1; k <= 16; k++) {
        float* dst = (k & 1) ? xA : out;   // step 16 (even) lands in d_out
        step_main<<<dim3(32,32,8), 256, 0, stream>>>(
            src, dst, alpha, prelife, filt, W0, b0, W1,
            stoch + (size_t)(k-1)*NPIX);
        step_mask<<<NPIX/256, 256, 0, stream>>>(dst, alpha, prelife, valid);
        src = dst;
    }
}

// Round 8
// 25607.251 us; speedup vs baseline: 5.6009x; 1.2771x over previous
//
#include <hip/hip_runtime.h>
#include <math.h>

// NCA: B=8, H=W=256, C=16, 16 steps. fp32.
// R7 post-mortem: 18x win (LDS-staged W0), but LDS-ISSUE-bound: 16-lane
// broadcast reads deliver 64 unique B per b128 wave-instr; LDS pipe ~0.94x
// VALU -> VALUBusy 19%.
// R8: 4px x 8j register tile per thread, k-quarter split.
//   thread=(quad 0..15, jg 0..3, kq 0..3): per 4k: 4 perc b128 + 8 w0s b128
//   + 128 FMA (ratio 0.56, 32 indep chains). h kq-reduced via shfl(1,2);
//   GEMM2 per-kq channel-quad (dx[4][4]); jg-reduce shfl(4,8).
//   w0s k-interleaved rows of 36 -> kq{0,4,8,12}+jg{0,8,16,24} = 32 banks,
//   conflict-free. LDS 52.2KB -> 3 blocks/CU. ~90 live regs, literal idx.

#define HW 256
#define NPIX (8*HW*HW)   // 524288

__device__ __forceinline__ float4 f4max(float4 a, float4 b) {
    return make_float4(fmaxf(a.x,b.x), fmaxf(a.y,b.y), fmaxf(a.z,b.z), fmaxf(a.w,b.w));
}

// Precompute sobel bank (6 filters, 7x7, normalized).
__global__ void init_kernel(const float* __restrict__ W0,
                            float* __restrict__ filt) {
    int t = blockIdx.x * blockDim.x + threadIdx.x;
    if (t < 6) {
        int f = t;
        int size = 3 + 2*(f >> 1);
        int p0 = (7 - size) >> 1;
        int isY = f & 1;
        float vals[49];
        float norm = 0.f;
        for (int a = 0; a < 7; a++) {
            for (int b = 0; b < 7; b++) {
                float v = 0.f;
                if (a >= p0 && a < p0+size && b >= p0 && b < p0+size) {
                    float fy = (float)(a - 3), fx = (float)(b - 3);
                    float den = fx*fx + fy*fy;
                    if (den == 0.f) den = 1.f;
                    v = (isY ? fy : fx) / den;
                }
                vals[a*7+b] = v;
                norm += fabsf(v);
            }
        }
        float inv = 1.f / norm;
        for (int i = 0; i < 49; i++) filt[f*49 + i] = vals[i] * inv;
    }
}

// One 8x8 pixel tile per block, 256 threads.
__launch_bounds__(256, 3)
__global__ void step_main(const float* __restrict__ x,
                          float* __restrict__ xmid,
                          float* __restrict__ alpha_out,
                          float* __restrict__ prelife_out,
                          const float* __restrict__ filt_g,
                          const float* __restrict__ W0,
                          const float* __restrict__ b0,
                          const float* __restrict__ W1,
                          const float* __restrict__ stoch_s) {
    // carve: phase1 [0,4214): xs 3920 + filt 294 | phase2 [0,4608): w0s
    //        perc [4608,13056)   -> 52224 B, 3 blocks/CU
    __shared__ float smem[13056];
    float* xs     = smem;          // 14*14*20 = 3920 (phase 1 only)
    float* filt_s = smem + 3920;   // 294 (phase 1 only)
    float* w0s    = smem;          // 128 rows x 36 = 4608 (phase 2 only)
    float* perc   = smem + 4608;   // 64 x 132 = 8448

    const int t   = threadIdx.x;
    const int b   = blockIdx.z;
    const int ty0 = blockIdx.y * 8;
    const int tx0 = blockIdx.x * 8;

    for (int i = t; i < 294; i += 256) filt_s[i] = filt_g[i];

    // stage x tile + halo (zero pad = conv's zero padding)
    for (int v = t; v < 784; v += 256) {          // 14*14*4 float4s
        int c4  = v & 3;
        int cell = v >> 2;
        int ly = cell / 14;
        int lx = cell - ly*14;
        int gy = ty0 + ly - 3, gx = tx0 + lx - 3;
        float4 val = make_float4(0.f,0.f,0.f,0.f);
        if ((unsigned)gy < 256u && (unsigned)gx < 256u)
            val = *(const float4*)&x[((((b<<8) + gy)<<8) + gx)*16 + (c4<<2)];
        *(float4*)&xs[cell*20 + (c4<<2)] = val;
    }
    __syncthreads();

    {   // ---- phase 1: conv + pools -> perc ----
        const int p  = t & 63;
        const int q  = t >> 6;
        const int py = p >> 3, px = p & 7;
        const int gy = ty0 + py, gx = tx0 + px;
        const int q4 = q << 2;

        float4 y4[6];
        #pragma unroll
        for (int f = 0; f < 6; f++) y4[f] = make_float4(0.f,0.f,0.f,0.f);

        #pragma unroll
        for (int a = 0; a < 7; a++) {
            #pragma unroll
            for (int bb = 0; bb < 7; bb++) {
                float4 xv = *(const float4*)&xs[((py+a)*14 + (px+bb))*20 + q4];
                #pragma unroll
                for (int f = 0; f < 6; f++) {
                    float w = filt_s[f*49 + a*7 + bb];
                    y4[f].x = fmaf(w, xv.x, y4[f].x);
                    y4[f].y = fmaf(w, xv.y, y4[f].y);
                    y4[f].z = fmaf(w, xv.z, y4[f].z);
                    y4[f].w = fmaf(w, xv.w, y4[f].w);
                }
            }
        }
        float4 m5 = make_float4(-INFINITY,-INFINITY,-INFINITY,-INFINITY);
        #pragma unroll
        for (int dy = -2; dy <= 2; dy++) {
            #pragma unroll
            for (int dx2 = -2; dx2 <= 2; dx2++) {
                if ((unsigned)(gy+dy) < 256u && (unsigned)(gx+dx2) < 256u)
                    m5 = f4max(m5, *(const float4*)&xs[((py+3+dy)*14 + (px+3+dx2))*20 + q4]);
            }
        }
        // perc: [0:16)=x, [16+f*16+c)=y (f-major), [112:128)=pool5
        float4 xc = *(const float4*)&xs[((py+3)*14 + (px+3))*20 + q4];
        *(float4*)&perc[p*132 + q4] = xc;
        #pragma unroll
        for (int f = 0; f < 6; f++)
            *(float4*)&perc[p*132 + 16 + f*16 + q4] = y4[f];
        *(float4*)&perc[p*132 + 112 + q4] = m5;

        if (q == 0) {
            float pre = -INFINITY;
            #pragma unroll
            for (int dy = -1; dy <= 1; dy++) {
                #pragma unroll
                for (int dx2 = -1; dx2 <= 1; dx2++) {
                    if ((unsigned)(gy+dy) < 256u && (unsigned)(gx+dx2) < 256u)
                        pre = fmaxf(pre, xs[((py+3+dy)*14 + (px+3+dx2))*20 + 3]);
                }
            }
            prelife_out[(b << 16) + (gy << 8) + gx] = (pre > 0.1f) ? 1.f : 0.f;
        }
    }
    // xs/filt dead after the next barrier; region becomes w0s.

    // ---- phase 2: MLP ----
    const int kq   = t & 3;         // k-quarter + output channel-quad
    const int jg   = (t >> 2) & 3;  // j-octet within 32-j chunk
    const int quad = t >> 4;        // pixel quad: owns px {quad+16i}
    const int jg8  = jg << 3;
    const int kq32 = kq << 5;

    const float* pp0 = &perc[(quad     ) * 132 + kq32];
    const float* pp1 = &perc[(quad + 16) * 132 + kq32];
    const float* pp2 = &perc[(quad + 32) * 132 + kq32];
    const float* pp3 = &perc[(quad + 48) * 132 + kq32];

    float dx[4][4];
    #pragma unroll
    for (int i = 0; i < 4; i++)
        #pragma unroll
        for (int c = 0; c < 4; c++) dx[i][c] = 0.f;

    #pragma unroll 1
    for (int jc = 0; jc < 8; jc++) {
        __syncthreads();   // prev chunk k-loop (or phase 1) done
        // stage W0[:, jc*32..+32) -> w0s, k-interleaved rows of 36:
        // global k -> row (k&31)*4 + (k>>5)
        #pragma unroll
        for (int r = 0; r < 4; r++) {
            int idx = (r << 8) + t;           // 0..1023 float4s
            int kg  = idx >> 3;
            int jp  = idx & 7;
            int drow = ((kg & 31) << 2) + (kg >> 5);
            *(float4*)&w0s[drow*36 + (jp << 2)] =
                *(const float4*)&W0[(kg << 8) + (jc << 5) + (jp << 2)];
        }
        __syncthreads();

        float h[4][8];
        #pragma unroll
        for (int i = 0; i < 4; i++)
            #pragma unroll
            for (int jj = 0; jj < 8; jj++) h[i][jj] = 0.f;

        #pragma unroll 1
        for (int k4 = 0; k4 < 32; k4 += 4) {
            float4 pA0 = *(const float4*)&pp0[k4];
            float4 pA1 = *(const float4*)&pp1[k4];
            float4 pA2 = *(const float4*)&pp2[k4];
            float4 pA3 = *(const float4*)&pp3[k4];
            #pragma unroll
            for (int kk = 0; kk < 4; kk++) {
                // literal kk -> component selects fold at compile time
                float a0 = kk==0?pA0.x : kk==1?pA0.y : kk==2?pA0.z : pA0.w;
                float a1 = kk==0?pA1.x : kk==1?pA1.y : kk==2?pA1.z : pA1.w;
                float a2 = kk==0?pA2.x : kk==1?pA2.y : kk==2?pA2.z : pA2.w;
                float a3 = kk==0?pA3.x : kk==1?pA3.y : kk==2?pA3.z : pA3.w;
                const float* wr = &w0s[((k4 + kk)*4 + kq)*36 + jg8];
                float4 wA = *(const float4*)wr;
                float4 wB = *(const float4*)(wr + 4);
                #pragma unroll
                for (int i = 0; i < 4; i++) {
                    float ai = i==0?a0 : i==1?a1 : i==2?a2 : a3;
                    h[i][0] = fmaf(ai, wA.x, h[i][0]);
                    h[i][1] = fmaf(ai, wA.y, h[i][1]);
                    h[i][2] = fmaf(ai, wA.z, h[i][2]);
                    h[i][3] = fmaf(ai, wA.w, h[i][3]);
                    h[i][4] = fmaf(ai, wB.x, h[i][4]);
                    h[i][5] = fmaf(ai, wB.y, h[i][5]);
                    h[i][6] = fmaf(ai, wB.z, h[i][6]);
                    h[i][7] = fmaf(ai, wB.w, h[i][7]);
                }
            }
        }
        // reduce h over the 4 kq lanes (bits 0-1)
        #pragma unroll
        for (int i = 0; i < 4; i++)
            #pragma unroll
            for (int jj = 0; jj < 8; jj++) {
                h[i][jj] += __shfl_xor(h[i][jj], 1);
                h[i][jj] += __shfl_xor(h[i][jj], 2);
            }
        // bias + relu (all kq lanes redundantly, consistent)
        const int jbase = (jc << 5) + jg8;
        float4 bA = *(const float4*)&b0[jbase];
        float4 bB = *(const float4*)&b0[jbase + 4];
        #pragma unroll
        for (int i = 0; i < 4; i++) {
            h[i][0] = fmaxf(h[i][0] + bA.x, 0.f);
            h[i][1] = fmaxf(h[i][1] + bA.y, 0.f);
            h[i][2] = fmaxf(h[i][2] + bA.z, 0.f);
            h[i][3] = fmaxf(h[i][3] + bA.w, 0.f);
            h[i][4] = fmaxf(h[i][4] + bB.x, 0.f);
            h[i][5] = fmaxf(h[i][5] + bB.y, 0.f);
            h[i][6] = fmaxf(h[i][6] + bB.z, 0.f);
            h[i][7] = fmaxf(h[i][7] + bB.w, 0.f);
        }
        // GEMM2: this lane's channel-quad kq*4..+4
        #pragma unroll
        for (int jj = 0; jj < 8; jj++) {
            float4 wv = *(const float4*)&W1[((jbase + jj) << 4) + (kq << 2)];
            #pragma unroll
            for (int i = 0; i < 4; i++) {
                dx[i][0] = fmaf(h[i][jj], wv.x, dx[i][0]);
                dx[i][1] = fmaf(h[i][jj], wv.y, dx[i][1]);
                dx[i][2] = fmaf(h[i][jj], wv.z, dx[i][2]);
                dx[i][3] = fmaf(h[i][jj], wv.w, dx[i][3]);
            }
        }
    }

    // reduce dx over the 4 jg lanes (bits 2-3)
    #pragma unroll
    for (int i = 0; i < 4; i++)
        #pragma unroll
        for (int c = 0; c < 4; c++) {
            dx[i][c] += __shfl_xor(dx[i][c], 4);
            dx[i][c] += __shfl_xor(dx[i][c], 8);
        }

    // writer: pixel quad+16*jg, channels kq*4..+4 (jg select = cndmask chain)
    float o0 = jg==0?dx[0][0] : jg==1?dx[1][0] : jg==2?dx[2][0] : dx[3][0];
    float o1 = jg==0?dx[0][1] : jg==1?dx[1][1] : jg==2?dx[2][1] : dx[3][1];
    float o2 = jg==0?dx[0][2] : jg==1?dx[1][2] : jg==2?dx[2][2] : dx[3][2];
    float o3 = jg==0?dx[0][3] : jg==1?dx[1][3] : jg==2?dx[2][3] : dx[3][3];

    const int pw  = quad + (jg << 4);
    const int ppy = pw >> 3, ppx = pw & 7;
    const int pix2 = (b << 16) + ((ty0 + ppy) << 8) + (tx0 + ppx);
    float fire = (stoch_s[pix2] > 0.5f) ? 1.f : 0.f;
    float4 xc2 = *(const float4*)&perc[pw*132 + (kq << 2)];
    float4 xn;
    xn.x = fmaf(fire, o0, xc2.x);
    xn.y = fmaf(fire, o1, xc2.y);
    xn.z = fmaf(fire, o2, xc2.z);
    xn.w = fmaf(fire, o3, xc2.w);
    *(float4*)&xmid[((size_t)pix2 << 4) + (kq << 2)] = xn;
    if (kq == 0) alpha_out[pix2] = xn.w;   // channel 3
}

// In-place life masking: reads alpha_new from the separate plane (race-free).
__global__ void step_mask(float* __restrict__ xbuf,
                          const float* __restrict__ alpha,
                          const float* __restrict__ prelife,
                          const float* __restrict__ valid) {
    int pix = blockIdx.x * 256 + threadIdx.x;
    int b = pix >> 16;
    int y = (pix >> 8) & 255;
    int x = pix & 255;
    float m = -INFINITY;
    #pragma unroll
    for (int dy = -1; dy <= 1; dy++) {
        #pragma unroll
        for (int dxo = -1; dxo <= 1; dxo++) {
            int yy = y + dy, xx = x + dxo;
            if ((unsigned)yy < 256u && (unsigned)xx < 256u)
                m = fmaxf(m, alpha[(b << 16) + (yy << 8) + xx]);
        }
    }
    float life = (prelife[pix] != 0.f && m > 0.1f) ? 1.f : 0.f;
    float s = life * valid[pix];
    float4* xp = (float4*)&xbuf[(size_t)pix << 4];
    #pragma unroll
    for (int i = 0; i < 4; i++) {
        float4 v = xp[i];
        v.x *= s; v.y *= s; v.z *= s; v.w *= s;
        xp[i] = v;
    }
}

extern "C" void kernel_launch(void* const* d_in, const int* in_sizes, int n_in,
                              void* d_out, int out_size, void* d_ws, size_t ws_size,
                              hipStream_t stream) {
    const float* x0    = (const float*)d_in[0];
    const float* valid = (const float*)d_in[1];
    const float* stoch = (const float*)d_in[2];
    const float* W0    = (const float*)d_in[3];
    const float* b0    = (const float*)d_in[4];
    const float* W1    = (const float*)d_in[5];

    float* ws      = (float*)d_ws;
    float* xA      = ws;                 // 8388608 floats
    float* alpha   = ws + 8388608;       // 524288
    float* prelife = ws + 8912896;       // 524288
    float* filt    = ws + 9437184;       // 294 (+pad)
    float* out     = (float*)d_out;

    init_kernel<<<1, 64, 0, stream>>>(W0, filt);

    const float* src = x0;
    for (int k = 1; k <= 16; k++) {
        float* dst = (k & 1) ? xA : out;   // step 16 (even) lands in d_out
        step_main<<<dim3(32,32,8), 256, 0, stream>>>(
            src, dst, alpha, prelife, filt, W0, b0, W1,
            stoch + (size_t)(k-1)*NPIX);
        step_mask<<<NPIX/256, 256, 0, stream>>>(dst, alpha, prelife, valid);
        src = dst;
    }
}

// Round 10
// 19970.244 us; speedup vs baseline: 7.1819x; 1.2823x over previous
//
#include <hip/hip_runtime.h>
#include <math.h>

// NCA: B=8, H=W=256, C=16, 16 steps. fp32.
// R9 post-mortem: PST=136 < layout span 140 -> pool5 tail (offsets 136..139)
// overwrote pixel p+1's x-channels = phase-1 LDS race -> absmax 6.
// R10: PST=140 (row fits 3*36+32=140; 140%32=12 -> phase-2 reads max 3-way).
// Keeps R9's T14 async-stage, k4 unroll 2, w0s k-interleave.

#define HW 256
#define NPIX (8*HW*HW)   // 524288
#define PST 140          // perc row stride (floats); must be >= 140, mult of 4
#define GST 36           // perc k-group stride (floats)

__device__ __forceinline__ float4 f4max(float4 a, float4 b) {
    return make_float4(fmaxf(a.x,b.x), fmaxf(a.y,b.y), fmaxf(a.z,b.z), fmaxf(a.w,b.w));
}

// Precompute sobel bank (6 filters, 7x7, normalized).
__global__ void init_kernel(const float* __restrict__ W0,
                            float* __restrict__ filt) {
    int t = blockIdx.x * blockDim.x + threadIdx.x;
    if (t < 6) {
        int f = t;
        int size = 3 + 2*(f >> 1);
        int p0 = (7 - size) >> 1;
        int isY = f & 1;
        float vals[49];
        float norm = 0.f;
        for (int a = 0; a < 7; a++) {
            for (int b = 0; b < 7; b++) {
                float v = 0.f;
                if (a >= p0 && a < p0+size && b >= p0 && b < p0+size) {
                    float fy = (float)(a - 3), fx = (float)(b - 3);
                    float den = fx*fx + fy*fy;
                    if (den == 0.f) den = 1.f;
                    v = (isY ? fy : fx) / den;
                }
                vals[a*7+b] = v;
                norm += fabsf(v);
            }
        }
        float inv = 1.f / norm;
        for (int i = 0; i < 49; i++) filt[f*49 + i] = vals[i] * inv;
    }
}

// One 8x8 pixel tile per block, 256 threads.
__launch_bounds__(256, 3)
__global__ void step_main(const float* __restrict__ x,
                          float* __restrict__ xmid,
                          float* __restrict__ alpha_out,
                          float* __restrict__ prelife_out,
                          const float* __restrict__ filt_g,
                          const float* __restrict__ W0,
                          const float* __restrict__ b0,
                          const float* __restrict__ W1,
                          const float* __restrict__ stoch_s) {
    // carve: phase1 [0,4214): xs 3920 + filt 294 | phase2 [0,4608): w0s
    //        perc [4608,13568)  -> 54272 B total, 3 blocks/CU @160KB pool
    __shared__ float smem[13568];
    float* xs     = smem;          // 14*14*20 = 3920 (phase 1 only)
    float* filt_s = smem + 3920;   // 294 (phase 1 only)
    float* w0s    = smem;          // 128 rows x 36 = 4608 (phase 2 only)
    float* perc   = smem + 4608;   // 64 x 140 = 8960

    const int t   = threadIdx.x;
    const int b   = blockIdx.z;
    const int ty0 = blockIdx.y * 8;
    const int tx0 = blockIdx.x * 8;

    for (int i = t; i < 294; i += 256) filt_s[i] = filt_g[i];

    // stage x tile + halo (zero pad = conv's zero padding)
    for (int v = t; v < 784; v += 256) {          // 14*14*4 float4s
        int c4  = v & 3;
        int cell = v >> 2;
        int ly = cell / 14;
        int lx = cell - ly*14;
        int gy = ty0 + ly - 3, gx = tx0 + lx - 3;
        float4 val = make_float4(0.f,0.f,0.f,0.f);
        if ((unsigned)gy < 256u && (unsigned)gx < 256u)
            val = *(const float4*)&x[((((b<<8) + gy)<<8) + gx)*16 + (c4<<2)];
        *(float4*)&xs[cell*20 + (c4<<2)] = val;
    }
    __syncthreads();

    {   // ---- phase 1: conv + pools -> perc ----
        const int p  = t & 63;
        const int q  = t >> 6;
        const int py = p >> 3, px = p & 7;
        const int gy = ty0 + py, gx = tx0 + px;
        const int q4 = q << 2;

        float4 y4[6];
        #pragma unroll
        for (int f = 0; f < 6; f++) y4[f] = make_float4(0.f,0.f,0.f,0.f);

        #pragma unroll
        for (int a = 0; a < 7; a++) {
            #pragma unroll
            for (int bb = 0; bb < 7; bb++) {
                float4 xv = *(const float4*)&xs[((py+a)*14 + (px+bb))*20 + q4];
                #pragma unroll
                for (int f = 0; f < 6; f++) {
                    float w = filt_s[f*49 + a*7 + bb];
                    y4[f].x = fmaf(w, xv.x, y4[f].x);
                    y4[f].y = fmaf(w, xv.y, y4[f].y);
                    y4[f].z = fmaf(w, xv.z, y4[f].z);
                    y4[f].w = fmaf(w, xv.w, y4[f].w);
                }
            }
        }
        float4 m5 = make_float4(-INFINITY,-INFINITY,-INFINITY,-INFINITY);
        #pragma unroll
        for (int dy = -2; dy <= 2; dy++) {
            #pragma unroll
            for (int dx2 = -2; dx2 <= 2; dx2++) {
                if ((unsigned)(gy+dy) < 256u && (unsigned)(gx+dx2) < 256u)
                    m5 = f4max(m5, *(const float4*)&xs[((py+3+dy)*14 + (px+3+dx2))*20 + q4]);
            }
        }
        // perc channel c stored at (c>>5)*GST + (c&31):
        // x -> q4 ; y_f -> {16,36,52,72,88,108}[f]+q4 ; pool5 -> 124+q4
        // (max offset 124+12+3 = 139 < PST=140)
        float4 xc = *(const float4*)&xs[((py+3)*14 + (px+3))*20 + q4];
        *(float4*)&perc[p*PST + q4] = xc;
        const int offY[6] = {16, 36, 52, 72, 88, 108};
        #pragma unroll
        for (int f = 0; f < 6; f++)
            *(float4*)&perc[p*PST + offY[f] + q4] = y4[f];
        *(float4*)&perc[p*PST + 124 + q4] = m5;

        if (q == 0) {
            float pre = -INFINITY;
            #pragma unroll
            for (int dy = -1; dy <= 1; dy++) {
                #pragma unroll
                for (int dx2 = -1; dx2 <= 1; dx2++) {
                    if ((unsigned)(gy+dy) < 256u && (unsigned)(gx+dx2) < 256u)
                        pre = fmaxf(pre, xs[((py+3+dy)*14 + (px+3+dx2))*20 + 3]);
                }
            }
            prelife_out[(b << 16) + (gy << 8) + gx] = (pre > 0.1f) ? 1.f : 0.f;
        }
    }

    // ---- phase 2: MLP ----
    const int kq   = t & 3;         // k-quarter + output channel-quad
    const int jg   = (t >> 2) & 3;  // j-octet within 32-j chunk
    const int quad = t >> 4;        // pixel quad: owns px {quad+16i}
    const int jg8  = jg << 3;

    const float* pp0 = &perc[(quad     ) * PST + kq*GST];
    const float* pp1 = &perc[(quad + 16) * PST + kq*GST];
    const float* pp2 = &perc[(quad + 32) * PST + kq*GST];
    const float* pp3 = &perc[(quad + 48) * PST + kq*GST];

    // staging addresses: thread handles float4 idx r*256+t of each chunk
    const float* pW   = W0 + ((t >> 3) << 8) + ((t & 7) << 2);
    const int   wbase = (t >> 3) * 144 + ((t & 7) << 2);

    float dx[4][4];
    #pragma unroll
    for (int i = 0; i < 4; i++)
        #pragma unroll
        for (int c = 0; c < 4; c++) dx[i][c] = 0.f;

    // prologue: stage chunk 0
    float4 st0 = *(const float4*)(pW);
    float4 st1 = *(const float4*)(pW +  8192);
    float4 st2 = *(const float4*)(pW + 16384);
    float4 st3 = *(const float4*)(pW + 24576);
    __syncthreads();   // phase-1 xs reads done + perc complete (all waves)
    *(float4*)&w0s[wbase      ] = st0;
    *(float4*)&w0s[wbase +  36] = st1;
    *(float4*)&w0s[wbase +  72] = st2;
    *(float4*)&w0s[wbase + 108] = st3;
    __syncthreads();

    #pragma unroll 1
    for (int jc = 0; jc < 8; jc++) {
        // T14: issue next chunk's loads now; latency hides under the FMAs
        if (jc < 7) {
            const float* pN = pW + ((jc + 1) << 5);
            st0 = *(const float4*)(pN);
            st1 = *(const float4*)(pN +  8192);
            st2 = *(const float4*)(pN + 16384);
            st3 = *(const float4*)(pN + 24576);
        }

        float h[4][8];
        #pragma unroll
        for (int i = 0; i < 4; i++)
            #pragma unroll
            for (int jj = 0; jj < 8; jj++) h[i][jj] = 0.f;

        #pragma unroll 2
        for (int k4 = 0; k4 < 32; k4 += 4) {
            float4 pA0 = *(const float4*)&pp0[k4];
            float4 pA1 = *(const float4*)&pp1[k4];
            float4 pA2 = *(const float4*)&pp2[k4];
            float4 pA3 = *(const float4*)&pp3[k4];
            #pragma unroll
            for (int kk = 0; kk < 4; kk++) {
                float a0 = kk==0?pA0.x : kk==1?pA0.y : kk==2?pA0.z : pA0.w;
                float a1 = kk==0?pA1.x : kk==1?pA1.y : kk==2?pA1.z : pA1.w;
                float a2 = kk==0?pA2.x : kk==1?pA2.y : kk==2?pA2.z : pA2.w;
                float a3 = kk==0?pA3.x : kk==1?pA3.y : kk==2?pA3.z : pA3.w;
                const float* wr = &w0s[((k4 + kk)*4 + kq)*36 + jg8];
                float4 wA = *(const float4*)wr;
                float4 wB = *(const float4*)(wr + 4);
                #pragma unroll
                for (int i = 0; i < 4; i++) {
                    float ai = i==0?a0 : i==1?a1 : i==2?a2 : a3;
                    h[i][0] = fmaf(ai, wA.x, h[i][0]);
                    h[i][1] = fmaf(ai, wA.y, h[i][1]);
                    h[i][2] = fmaf(ai, wA.z, h[i][2]);
                    h[i][3] = fmaf(ai, wA.w, h[i][3]);
                    h[i][4] = fmaf(ai, wB.x, h[i][4]);
                    h[i][5] = fmaf(ai, wB.y, h[i][5]);
                    h[i][6] = fmaf(ai, wB.z, h[i][6]);
                    h[i][7] = fmaf(ai, wB.w, h[i][7]);
                }
            }
        }
        // reduce h over the 4 kq lanes (bits 0-1)
        #pragma unroll
        for (int i = 0; i < 4; i++)
            #pragma unroll
            for (int jj = 0; jj < 8; jj++) {
                h[i][jj] += __shfl_xor(h[i][jj], 1);
                h[i][jj] += __shfl_xor(h[i][jj], 2);
            }
        // bias + relu
        const int jbase = (jc << 5) + jg8;
        float4 bA = *(const float4*)&b0[jbase];
        float4 bB = *(const float4*)&b0[jbase + 4];
        #pragma unroll
        for (int i = 0; i < 4; i++) {
            h[i][0] = fmaxf(h[i][0] + bA.x, 0.f);
            h[i][1] = fmaxf(h[i][1] + bA.y, 0.f);
            h[i][2] = fmaxf(h[i][2] + bA.z, 0.f);
            h[i][3] = fmaxf(h[i][3] + bA.w, 0.f);
            h[i][4] = fmaxf(h[i][4] + bB.x, 0.f);
            h[i][5] = fmaxf(h[i][5] + bB.y, 0.f);
            h[i][6] = fmaxf(h[i][6] + bB.z, 0.f);
            h[i][7] = fmaxf(h[i][7] + bB.w, 0.f);
        }
        // GEMM2: this lane's channel-quad kq*4..+4
        #pragma unroll
        for (int jj = 0; jj < 8; jj++) {
            float4 wv = *(const float4*)&W1[((jbase + jj) << 4) + (kq << 2)];
            #pragma unroll
            for (int i = 0; i < 4; i++) {
                dx[i][0] = fmaf(h[i][jj], wv.x, dx[i][0]);
                dx[i][1] = fmaf(h[i][jj], wv.y, dx[i][1]);
                dx[i][2] = fmaf(h[i][jj], wv.z, dx[i][2]);
                dx[i][3] = fmaf(h[i][jj], wv.w, dx[i][3]);
            }
        }

        __syncthreads();   // all reads of w0s done before overwrite
        if (jc < 7) {
            *(float4*)&w0s[wbase      ] = st0;
            *(float4*)&w0s[wbase +  36] = st1;
            *(float4*)&w0s[wbase +  72] = st2;
            *(float4*)&w0s[wbase + 108] = st3;
            __syncthreads();
        }
    }

    // reduce dx over the 4 jg lanes (bits 2-3)
    #pragma unroll
    for (int i = 0; i < 4; i++)
        #pragma unroll
        for (int c = 0; c < 4; c++) {
            dx[i][c] += __shfl_xor(dx[i][c], 4);
            dx[i][c] += __shfl_xor(dx[i][c], 8);
        }

    // writer: pixel quad+16*jg, channels kq*4..+4
    float o0 = jg==0?dx[0][0] : jg==1?dx[1][0] : jg==2?dx[2][0] : dx[3][0];
    float o1 = jg==0?dx[0][1] : jg==1?dx[1][1] : jg==2?dx[2][1] : dx[3][1];
    float o2 = jg==0?dx[0][2] : jg==1?dx[1][2] : jg==2?dx[2][2] : dx[3][2];
    float o3 = jg==0?dx[0][3] : jg==1?dx[1][3] : jg==2?dx[2][3] : dx[3][3];

    const int pw  = quad + (jg << 4);
    const int ppy = pw >> 3, ppx = pw & 7;
    const int pix2 = (b << 16) + ((ty0 + ppy) << 8) + (tx0 + ppx);
    float fire = (stoch_s[pix2] > 0.5f) ? 1.f : 0.f;
    float4 xc2 = *(const float4*)&perc[pw*PST + (kq << 2)];
    float4 xn;
    xn.x = fmaf(fire, o0, xc2.x);
    xn.y = fmaf(fire, o1, xc2.y);
    xn.z = fmaf(fire, o2, xc2.z);
    xn.w = fmaf(fire, o3, xc2.w);
    *(float4*)&xmid[((size_t)pix2 << 4) + (kq << 2)] = xn;
    if (kq == 0) alpha_out[pix2] = xn.w;   // channel 3
}

// In-place life masking: reads alpha_new from the separate plane (race-free).
__global__ void step_mask(float* __restrict__ xbuf,
                          const float* __restrict__ alpha,
                          const float* __restrict__ prelife,
                          const float* __restrict__ valid) {
    int pix = blockIdx.x * 256 + threadIdx.x;
    int b = pix >> 16;
    int y = (pix >> 8) & 255;
    int x = pix & 255;
    float m = -INFINITY;
    #pragma unroll
    for (int dy = -1; dy <= 1; dy++) {
        #pragma unroll
        for (int dxo = -1; dxo <= 1; dxo++) {
            int yy = y + dy, xx = x + dxo;
            if ((unsigned)yy < 256u && (unsigned)xx < 256u)
                m = fmaxf(m, alpha[(b << 16) + (yy << 8) + xx]);
        }
    }
    float life = (prelife[pix] != 0.f && m > 0.1f) ? 1.f : 0.f;
    float s = life * valid[pix];
    float4* xp = (float4*)&xbuf[(size_t)pix << 4];
    #pragma unroll
    for (int i = 0; i < 4; i++) {
        float4 v = xp[i];
        v.x *= s; v.y *= s; v.z *= s; v.w *= s;
        xp[i] = v;
    }
}

extern "C" void kernel_launch(void* const* d_in, const int* in_sizes, int n_in,
                              void* d_out, int out_size, void* d_ws, size_t ws_size,
                              hipStream_t stream) {
    const float* x0    = (const float*)d_in[0];
    const float* valid = (const float*)d_in[1];
    const float* stoch = (const float*)d_in[2];
    const float* W0    = (const float*)d_in[3];
    const float* b0    = (const float*)d_in[4];
    const float* W1    = (const float*)d_in[5];

    float* ws      = (float*)d_ws;
    float* xA      = ws;                 // 8388608 floats
    float* alpha   = ws + 8388608;       // 524288
    float* prelife = ws + 8912896;       // 524288
    float* filt    = ws + 9437184;       // 294 (+pad)
    float* out     = (float*)d_out;

    init_kernel<<<1, 64, 0, stream>>>(W0, filt);

    const float* src = x0;
    for (int k = 1; k <= 16; k++) {
        float* dst = (k & 1) ? xA : out;   // step 16 (even) lands in d_out
        step_main<<<dim3(32,32,8), 256, 0, stream>>>(
            src, dst, alpha, prelife, filt, W0, b0, W1,
            stoch + (size_t)(k-1)*NPIX);
        step_mask<<<NPIX/256, 256, 0, stream>>>(dst, alpha, prelife, valid);
        src = dst;
    }
}